// Round 1
// baseline (954.908 us; speedup 1.0000x reference)
//
#include <hip/hip_runtime.h>
#include <stdint.h>

// Problem constants (from reference):
//   NUM_BLOCKS=8192, BLOCK_SIZE=16  -> NUM_SLOTS = 131072
//   NUM_HEADS=8, HEAD_SIZE=128      -> TOKEN_FLOATS = 1024 (4 KiB per slot)
//   NUM_TOKENS=65536
// Output = kv_cache with to_cache scattered at slot_mapping. We invert the
// mapping so every output slot is written exactly once (1.0 GiB total HBM
// traffic instead of 1.5 GiB for copy-then-scatter).

#define TOKEN_F4 256  // 1024 floats = 256 float4 per slot
#define SLOTS_PER_BLOCK 8

__global__ __launch_bounds__(256) void build_inverse_kernel(
    const int* __restrict__ slot_mapping,
    int* __restrict__ inv,
    int num_tokens)
{
    int i = blockIdx.x * blockDim.x + threadIdx.x;
    if (i < num_tokens) {
        inv[slot_mapping[i]] = i;
    }
}

__global__ __launch_bounds__(256) void gather_write_kernel(
    const float4* __restrict__ to_cache,
    const float4* __restrict__ kv_cache,
    const int* __restrict__ inv,
    float4* __restrict__ out,
    int num_slots)
{
    const int tid = threadIdx.x;  // 0..255, one float4 per thread per slot
    int slot0 = blockIdx.x * SLOTS_PER_BLOCK;

    #pragma unroll
    for (int s = 0; s < SLOTS_PER_BLOCK; ++s) {
        int slot = slot0 + s;
        if (slot >= num_slots) return;
        int tok = inv[slot];  // uniform across block -> scalar load
        const float4* __restrict__ src =
            (tok >= 0) ? (to_cache + (size_t)tok * TOKEN_F4)
                       : (kv_cache + (size_t)slot * TOKEN_F4);
        out[(size_t)slot * TOKEN_F4 + tid] = src[tid];
    }
}

extern "C" void kernel_launch(void* const* d_in, const int* in_sizes, int n_in,
                              void* d_out, int out_size, void* d_ws, size_t ws_size,
                              hipStream_t stream) {
    const float* to_cache = (const float*)d_in[0];      // [num_tokens, 8, 128]
    const float* kv_cache = (const float*)d_in[1];      // [8192, 16, 8, 128]
    const int* slot_mapping = (const int*)d_in[2];      // [num_tokens]
    float* out = (float*)d_out;

    const int num_tokens = in_sizes[2];
    const int num_slots = out_size / 1024;  // 131072 slots of 1024 floats

    int* inv = (int*)d_ws;  // num_slots ints (512 KiB) of scratch

    // 0xFFFFFFFF == -1 in int32: mark all slots "no token".
    hipMemsetAsync(inv, 0xFF, (size_t)num_slots * sizeof(int), stream);

    build_inverse_kernel<<<(num_tokens + 255) / 256, 256, 0, stream>>>(
        slot_mapping, inv, num_tokens);

    int grid = (num_slots + SLOTS_PER_BLOCK - 1) / SLOTS_PER_BLOCK;  // 16384
    gather_write_kernel<<<grid, 256, 0, stream>>>(
        (const float4*)to_cache, (const float4*)kv_cache, inv,
        (float4*)out, num_slots);
}